// Round 3
// baseline (304.214 us; speedup 1.0000x reference)
//
#include <hip/hip_runtime.h>
#include <hip/hip_bf16.h>
#include <hip/hip_cooperative_groups.h>

namespace cg = cooperative_groups;

// ---------- constants (problem-fixed) ----------
#define NNODES 10000
#define NEDGES 80000
#define OBS    128
#define HID    1024
#define ACTD   8
#define NGR    64

typedef __bf16 bf16x8 __attribute__((ext_vector_type(8)));
typedef float  f32x4  __attribute__((ext_vector_type(4)));
typedef const __attribute__((address_space(1))) unsigned int gl_u32;
typedef __attribute__((address_space(3))) unsigned int lds_u32;

__device__ __forceinline__ ushort f2b(float f) {       // f32 -> bf16 (RNE)
    union { float f; unsigned int i; } v; v.f = f;
    unsigned int lsb = (v.i >> 16) & 1u;
    unsigned int r = v.i + 0x7fffu + lsb;
    return (ushort)(r >> 16);
}
__device__ __forceinline__ int cix(int v, int hi) {    // clamp index to [0, hi)
    return v < 0 ? 0 : (v >= hi ? hi - 1 : v);
}

// ---------- fused prep: zero accumulators + weight prep, block-partitioned ----------
//  blocks [0,128):   transpose+cast W1 [OBS x HID] -> Wt1 [HID x OBS] bf16
//  blocks [128,385): M2bf[i][:] = bf16(W2[i,:] @ Wl); row HID -> b2l = b2@Wl + bl
//  blocks [385,698): zero zacc / pool / cnt / degi / done
__global__ __launch_bounds__(256) void k_prep(const float* __restrict__ W1,
                                              const float* __restrict__ W2,
                                              const float* __restrict__ Wl,
                                              const float* __restrict__ b2,
                                              const float* __restrict__ bl,
                                              ushort* __restrict__ Wt1,
                                              ushort* __restrict__ M2bf,
                                              float* __restrict__ b2l,
                                              float* __restrict__ zacc,
                                              float* __restrict__ pool,
                                              float* __restrict__ cnt,
                                              int* __restrict__ degi,
                                              int* __restrict__ done) {
    int blk = blockIdx.x;
    if (blk >= 385) {
        int idx = (blk - 385) * 256 + threadIdx.x;
        if (idx < NNODES * ACTD) zacc[idx] = 0.0f;
        if (idx < NGR * ACTD) pool[idx] = 0.0f;
        if (idx < NGR) cnt[idx] = 0.0f;
        if (idx < NNODES) degi[idx] = 0;
        if (idx == 0) *done = 0;
        return;
    }
    if (blk < 128) {
        __shared__ float tile[32][33];
        int bx = (blk & 31) * 32, by = (blk >> 5) * 32;  // bx over HID, by over OBS
        int tx = threadIdx.x & 31, ty = threadIdx.x >> 5;
        #pragma unroll
        for (int i = 0; i < 32; i += 8)
            tile[ty + i][tx] = W1[(size_t)(by + ty + i) * HID + bx + tx];
        __syncthreads();
        #pragma unroll
        for (int i = 0; i < 32; i += 8)
            Wt1[(size_t)(bx + ty + i) * OBS + by + tx] = f2b(tile[tx][ty + i]);
        return;
    }
    int wvid = ((blk - 128) * 256 + (int)threadIdx.x) >> 6;
    int lane = threadIdx.x & 63;
    if (wvid > HID) return;
    const float* row = (wvid == HID) ? b2 : (W2 + (size_t)wvid * HID);
    float acc[ACTD];
    #pragma unroll
    for (int j = 0; j < ACTD; ++j) acc[j] = 0.0f;
    for (int it = 0; it < HID / 64; ++it) {
        int k = it * 64 + lane;
        float w2v = row[k];
        float4 a = *(const float4*)(Wl + (size_t)k * ACTD);
        float4 b = *(const float4*)(Wl + (size_t)k * ACTD + 4);
        acc[0] += w2v * a.x; acc[1] += w2v * a.y; acc[2] += w2v * a.z; acc[3] += w2v * a.w;
        acc[4] += w2v * b.x; acc[5] += w2v * b.y; acc[6] += w2v * b.z; acc[7] += w2v * b.w;
    }
    #pragma unroll
    for (int off = 32; off > 0; off >>= 1)
        #pragma unroll
        for (int j = 0; j < ACTD; ++j)
            acc[j] += __shfl_down(acc[j], off);
    if (lane == 0) {
        if (wvid == HID) {
            #pragma unroll
            for (int j = 0; j < ACTD; ++j) b2l[j] = acc[j] + bl[j];
        } else {
            #pragma unroll
            for (int j = 0; j < ACTD; ++j) M2bf[wvid * ACTD + j] = f2b(acc[j]);
        }
    }
}

// ---------- cooperative graph build: count -> scan(+dinv) -> offsets -> fill ----------
// 320 blocks x 256. Distributed 3-level scan replaces the old 1-block k_scan.
__global__ __launch_bounds__(256) void k_graph(const int* __restrict__ src,
                                               const int* __restrict__ dst,
                                               int* __restrict__ degi,
                                               float* __restrict__ dinv,
                                               int* __restrict__ rowptr,
                                               int* __restrict__ cursor,
                                               int* __restrict__ chunksum,
                                               int* __restrict__ esrc,
                                               float* __restrict__ coefs,
                                               int e) {
    cg::grid_group grid = cg::this_grid();
    const int t = threadIdx.x, b = blockIdx.x;
    const int gid = b * 256 + t;

    // P1: degree count
    if (gid < e) atomicAdd(&degi[cix(dst[gid], NNODES)], 1);
    grid.sync();

    // P2: dinv + per-chunk (256-wide) exclusive scan; chunk b handled by block b<40
    __shared__ int wsum[4];
    if (b < 40) {
        int i = b * 256 + t;
        int v = 0;
        if (i < NNODES) { v = degi[i]; dinv[i] = rsqrtf((float)(v + 1)); } // +1 self-loop
        int lane = t & 63, w = t >> 6;
        int sc = v;                                      // inclusive wave scan
        #pragma unroll
        for (int off = 1; off < 64; off <<= 1) {
            int u = __shfl_up(sc, off);
            if (lane >= off) sc += u;
        }
        if (lane == 63) wsum[w] = sc;
        __syncthreads();
        int wo = 0;
        #pragma unroll
        for (int k = 0; k < 4; ++k) if (k < w) wo += wsum[k];
        if (i < NNODES) rowptr[i] = wo + sc - v;         // chunk-local exclusive prefix
        if (t == 255) chunksum[b] = wo + sc;             // chunk total
    }
    grid.sync();

    // P3: block 0, one wave scans the 40 chunk totals -> exclusive chunk offsets
    if (b == 0 && t < 64) {
        int v = (t < 40) ? chunksum[t] : 0;
        int sc = v;
        #pragma unroll
        for (int off = 1; off < 64; off <<= 1) {
            int u = __shfl_up(sc, off);
            if (t >= off) sc += u;
        }
        if (t < 40) chunksum[t] = sc - v;
        if (t == 39) rowptr[NNODES] = sc;                // = total edge count
    }
    grid.sync();

    // P4: apply chunk offsets -> final rowptr + cursor
    if (b < 40) {
        int i = b * 256 + t;
        if (i < NNODES) {
            int r = rowptr[i] + chunksum[b];
            rowptr[i] = r; cursor[i] = r;
        }
    }
    grid.sync();

    // P5: bucket edges by dst: sorted src + coef
    if (gid < e) {
        int s = cix(src[gid], NNODES), d = cix(dst[gid], NNODES);
        int pos = atomicAdd(&cursor[d], 1);
        esrc[pos] = s;
        coefs[pos] = dinv[s] * dinv[d];
    }
}

// ---------- layer-1 aggregation: CSR gather, one wave per node ----------
// lanes 0-31 process even edges, lanes 32-63 odd edges (float4/lane = full row per half);
// cross-half shfl reduce at the end. 2 edges per load instruction -> 2x MLP, half the trips.
__global__ void k_aggx(const float* __restrict__ x, const float* __restrict__ dinv,
                       const int* __restrict__ rowptr, const int* __restrict__ esrc,
                       const float* __restrict__ coefs, ushort* __restrict__ aggbf, int n) {
    int wv = (blockIdx.x * 256 + threadIdx.x) >> 6;
    int lane = threadIdx.x & 63;
    if (wv >= n) return;
    int half = lane >> 5, c = lane & 31;
    float d = dinv[wv];
    float4 v = make_float4(0.f, 0.f, 0.f, 0.f);
    if (half == 0) {                                     // self-loop term, once
        float d2 = d * d;
        float4 xs = *(const float4*)(x + (size_t)wv * OBS + c * 4);
        v.x = xs.x * d2; v.y = xs.y * d2; v.z = xs.z * d2; v.w = xs.w * d2;
    }
    int e1 = rowptr[wv + 1];
    for (int e = rowptr[wv] + half; e < e1; e += 2) {
        int s = esrc[e];
        float cf = coefs[e];
        float4 a = *(const float4*)(x + (size_t)s * OBS + c * 4);
        v.x += a.x * cf; v.y += a.y * cf; v.z += a.z * cf; v.w += a.w * cf;
    }
    v.x += __shfl_down(v.x, 32);
    v.y += __shfl_down(v.y, 32);
    v.z += __shfl_down(v.z, 32);
    v.w += __shfl_down(v.w, 32);
    if (half == 0) {
        ushort4 o;
        o.x = f2b(v.x); o.y = f2b(v.y); o.z = f2b(v.z); o.w = f2b(v.w);
        *(ushort4*)(aggbf + (size_t)wv * OBS + c * 4) = o;
    }
}

// ---------- fused GEMM1 + relu + MFMA epilogue (@M2) -> zacc ----------
// block 256 (4 waves), tile 128x128, K=OBS=128, BK=64, async global->LDS staging.
// LDS union: As(8192h)+Bs(8192h) overlapped by stage(128x136h), + M2t(16x128h) = 38912 B
__global__ __launch_bounds__(256) void k_gemm1_fused(const ushort* __restrict__ A,
                                                     const ushort* __restrict__ Bt,
                                                     const float* __restrict__ bias,
                                                     const ushort* __restrict__ M2bf,
                                                     float* __restrict__ zacc,
                                                     int M) {
    __shared__ ushort buf[128 * 136 + 16 * 128];         // 38912 B
    ushort* As    = buf;                                 // hw [0, 8192)
    ushort* Bs    = buf + 8192;                          // hw [8192, 16384)
    ushort* stage = buf;                                 // hw [0, 17408) after K-loop
    ushort* M2t   = buf + 128 * 136;                     // hw [17408, 19456)

    const int t = threadIdx.x;
    const int bm = blockIdx.x, bn = blockIdx.y;
    const int lane = t & 63, wv = t >> 6;
    const int wm = (wv & 1) * 64, wn = (wv >> 1) * 64;
    const int l16 = lane & 15, kg = (lane >> 4) * 8;

    if (t < 128) {
        ushort4 a = *(const ushort4*)(M2bf + (size_t)(bn * 128 + t) * ACTD);
        ushort4 b = *(const ushort4*)(M2bf + (size_t)(bn * 128 + t) * ACTD + 4);
        M2t[0 * 128 + t] = a.x; M2t[1 * 128 + t] = a.y;
        M2t[2 * 128 + t] = a.z; M2t[3 * 128 + t] = a.w;
        M2t[4 * 128 + t] = b.x; M2t[5 * 128 + t] = b.y;
        M2t[6 * 128 + t] = b.z; M2t[7 * 128 + t] = b.w;
        #pragma unroll
        for (int j = 8; j < 16; ++j) M2t[j * 128 + t] = 0;
    }

    f32x4 acc[4][4];
    #pragma unroll
    for (int i = 0; i < 4; ++i)
        #pragma unroll
        for (int j = 0; j < 4; ++j)
            acc[i][j] = (f32x4){0.f, 0.f, 0.f, 0.f};

    const int rs = t >> 3;                               // 0..31
    const int cs = (t & 7) * 8;                          // hw col, 16B chunks
    #pragma unroll
    for (int kt = 0; kt < OBS; kt += 64) {
        #pragma unroll
        for (int p = 0; p < 4; ++p) {                    // 32 rows/pass
            int r = rs + p * 32;
            int gr = bm * 128 + r; if (gr >= M) gr = M - 1;   // clamp (row discarded later)
            __builtin_amdgcn_global_load_lds(
                (gl_u32*)(A + (size_t)gr * OBS + kt + cs),
                (lds_u32*)(As + r * 64 + cs), 16, 0, 0);
            int gn = bn * 128 + r;
            __builtin_amdgcn_global_load_lds(
                (gl_u32*)(Bt + (size_t)gn * OBS + kt + cs),
                (lds_u32*)(Bs + r * 64 + cs), 16, 0, 0);
        }
        __syncthreads();                                 // drains vmcnt + barrier
        #pragma unroll
        for (int k2 = 0; k2 < 64; k2 += 32) {
            bf16x8 af[4], bfr[4];
            #pragma unroll
            for (int i = 0; i < 4; ++i)
                af[i] = *(const bf16x8*)(As + (wm + i * 16 + l16) * 64 + k2 + kg);
            #pragma unroll
            for (int j = 0; j < 4; ++j)
                bfr[j] = *(const bf16x8*)(Bs + (wn + j * 16 + l16) * 64 + k2 + kg);
            #pragma unroll
            for (int i = 0; i < 4; ++i)
                #pragma unroll
                for (int j = 0; j < 4; ++j)
                    acc[i][j] = __builtin_amdgcn_mfma_f32_16x16x32_bf16(af[i], bfr[j], acc[i][j], 0, 0, 0);
        }
        __syncthreads();                                 // LDS reads done before overwrite
    }

    // relu(acc + bias) -> stage bf16; C/D layout: col=lane&15, row=(lane>>4)*4+reg
    #pragma unroll
    for (int i = 0; i < 4; ++i) {
        int rowb = wm + i * 16 + (lane >> 4) * 4;
        #pragma unroll
        for (int j = 0; j < 4; ++j) {
            int col = wn + j * 16 + l16;
            float bj = bias[bn * 128 + col];
            #pragma unroll
            for (int r = 0; r < 4; ++r)
                stage[(rowb + r) * 136 + col] = f2b(fmaxf(acc[i][j][r] + bj, 0.0f));
        }
    }
    __syncthreads();

    #pragma unroll
    for (int st = 0; st < 2; ++st) {
        int row0 = wv * 32 + st * 16;
        f32x4 z = (f32x4){0.f, 0.f, 0.f, 0.f};
        #pragma unroll
        for (int kt = 0; kt < 128; kt += 32) {
            bf16x8 a = *(const bf16x8*)(stage + (row0 + l16) * 136 + kt + kg);
            bf16x8 b = *(const bf16x8*)(M2t + l16 * 128 + kt + kg);
            z = __builtin_amdgcn_mfma_f32_16x16x32_bf16(a, b, z, 0, 0, 0);
        }
        if (l16 < ACTD) {
            int rowb = bm * 128 + row0 + (lane >> 4) * 4;
            #pragma unroll
            for (int r = 0; r < 4; ++r)
                if (rowb + r < M)
                    atomicAdd(&zacc[(size_t)(rowb + r) * ACTD + l16], z[r]);
        }
    }
}

// ---------- z-aggregation (gather) + tanh + hierarchical pool + last-block finalize ----------
// 313 blocks x 256 (32 nodes/block) -> all 256 CUs active; k_final folded in.
__global__ __launch_bounds__(256) void k_zfinal(const float* __restrict__ zacc,
                                                const float* __restrict__ dinv,
                                                const int* __restrict__ rowptr,
                                                const int* __restrict__ esrc,
                                                const float* __restrict__ coefs,
                                                const float* __restrict__ b2l,
                                                const int* __restrict__ batch,
                                                float* __restrict__ pool,
                                                float* __restrict__ cnt,
                                                int* __restrict__ done,
                                                float* __restrict__ out, int n) {
    __shared__ float part[NGR * ACTD];
    __shared__ int   partc[NGR];
    __shared__ int   lastblk;
    int t = threadIdx.x;
    part[t] = 0.0f; part[t + 256] = 0.0f;
    if (t < NGR) partc[t] = 0;
    __syncthreads();

    int idx = blockIdx.x * 256 + t;
    int i = idx >> 3, j = idx & 7;
    if (i < n) {
        float d = dinv[i];
        float v = zacc[idx] * d * d;
        int e0 = rowptr[i], e1 = rowptr[i + 1];
        for (int e = e0; e < e1; ++e)
            v += coefs[e] * zacc[(size_t)esrc[e] * ACTD + j];
        float tz = tanhf(v + b2l[j]);
        int g = cix(batch[i], NGR);
        atomicAdd(&part[g * ACTD + j], tz);
        if (j == 0) atomicAdd(&partc[g], 1);
    }
    __syncthreads();

    int i0 = (blockIdx.x * 256) >> 3;                    // always < n for this grid
    int i1 = (blockIdx.x * 256 + 255) >> 3;
    if (i1 >= n) i1 = n - 1;
    int g0 = cix(batch[i0], NGR), g1 = cix(batch[i1], NGR);
    int ng = g1 - g0 + 1;                                // sorted batch => contiguous
    for (int u = t; u < ng * ACTD; u += 256)
        atomicAdd(&pool[g0 * ACTD + u], part[g0 * ACTD + u]);
    for (int u = t; u < ng; u += 256) {
        int c = partc[g0 + u];
        if (c) atomicAdd(&cnt[g0 + u], (float)c);
    }

    // completion counter: last block computes the final means (replaces k_final)
    __threadfence();
    __syncthreads();
    if (t == 0) {
        unsigned old = __hip_atomic_fetch_add((unsigned int*)done, 1u,
                                              __ATOMIC_ACQ_REL, __HIP_MEMORY_SCOPE_AGENT);
        lastblk = (old == (unsigned)(gridDim.x - 1));
    }
    __syncthreads();
    if (lastblk) {
        for (int u = t; u < NGR * ACTD; u += 256) {
            float p = __hip_atomic_load(&pool[u], __ATOMIC_RELAXED, __HIP_MEMORY_SCOPE_AGENT);
            float c = __hip_atomic_load(&cnt[u >> 3], __ATOMIC_RELAXED, __HIP_MEMORY_SCOPE_AGENT);
            out[u] = p / fmaxf(c, 1.0f);
        }
    }
}

// ---------- launch ----------
extern "C" void kernel_launch(void* const* d_in, const int* in_sizes, int n_in,
                              void* d_out, int out_size, void* d_ws, size_t ws_size,
                              hipStream_t stream) {
    const float* x   = (const float*)d_in[0];
    const int*   ei  = (const int*)d_in[1];
    const int*   bat = (const int*)d_in[2];
    const float* W1  = (const float*)d_in[3];
    const float* b1  = (const float*)d_in[4];
    const float* W2  = (const float*)d_in[5];
    const float* b2v = (const float*)d_in[6];
    const float* Wl  = (const float*)d_in[7];
    const float* bl  = (const float*)d_in[8];
    float* out = (float*)d_out;

    int N = NNODES, E = NEDGES;
    const int* src = ei;
    const int* dst = ei + E;

    // workspace layout — ~4.3 MB total (all offsets multiples of 256 B)
    char* ws = (char*)d_ws;
    size_t off = 0;
    float*  pool   = (float*)(ws + off); off += 2048;
    float*  cnt    = (float*)(ws + off); off += 256;
    float*  dinv   = (float*)(ws + off); off += 40192;                   // N f32
    int*    degi   = (int*)(ws + off);   off += 40192;                   // N i32
    int*    rowptr = (int*)(ws + off);   off += 40448;                   // N+1 i32
    int*    cursor = (int*)(ws + off);   off += 40192;                   // N i32
    int*    esrc   = (int*)(ws + off);   off += (size_t)E * 4;           // 320000
    float*  coefs  = (float*)(ws + off); off += (size_t)E * 4;           // 320000
    float*  b2l    = (float*)(ws + off); off += 256;
    ushort* M2bf   = (ushort*)(ws + off); off += (size_t)HID * ACTD * 2; // 16384
    ushort* Wt1    = (ushort*)(ws + off); off += (size_t)HID * OBS * 2;  // 262144
    float*  zacc   = (float*)(ws + off); off += (size_t)N * ACTD * 4;    // 320000
    ushort* aggbf  = (ushort*)(ws + off); off += (size_t)N * OBS * 2;    // 2560000
    int*    chunks = (int*)(ws + off);   off += 256;                     // 40 i32
    int*    done   = (int*)(ws + off);   off += 256;                     // 1 i32

    // 1. fused zero + weight prep
    k_prep<<<698, 256, 0, stream>>>(W1, W2, Wl, b2v, bl, Wt1, M2bf, b2l,
                                    zacc, pool, cnt, degi, done);

    // 2. cooperative graph build: count -> scan(+dinv) -> offsets -> fill
    {
        void* args[] = {(void*)&src, (void*)&dst, (void*)&degi, (void*)&dinv,
                        (void*)&rowptr, (void*)&cursor, (void*)&chunks,
                        (void*)&esrc, (void*)&coefs, (void*)&E};
        hipLaunchCooperativeKernel((void*)k_graph, dim3(320), dim3(256),
                                   args, 0, stream);
    }

    // 3. layer-1 aggregation (gather) -> bf16
    k_aggx<<<(N * 64 + 255) / 256, 256, 0, stream>>>(x, dinv, rowptr, esrc, coefs, aggbf, N);

    // 4. fused GEMM1 + relu + @M2 -> zacc
    k_gemm1_fused<<<dim3((N + 127) / 128, HID / 128), 256, 0, stream>>>(
        aggbf, Wt1, b1, M2bf, zacc, N);

    // 5. z-aggregation (gather) + tanh + pool + finalize (k_final folded in)
    k_zfinal<<<(N * ACTD + 255) / 256, 256, 0, stream>>>(
        zacc, dinv, rowptr, esrc, coefs, b2l, bat, pool, cnt, done, out, N);
}

// Round 4
// 155.681 us; speedup vs baseline: 1.9541x; 1.9541x over previous
//
#include <hip/hip_runtime.h>
#include <hip/hip_bf16.h>

// ---------- constants (problem-fixed) ----------
#define NNODES 10000
#define NEDGES 80000
#define OBS    128
#define HID    1024
#define ACTD   8
#define NGR    64

typedef __bf16 bf16x8 __attribute__((ext_vector_type(8)));
typedef float  f32x4  __attribute__((ext_vector_type(4)));
typedef const __attribute__((address_space(1))) unsigned int gl_u32;
typedef __attribute__((address_space(3))) unsigned int lds_u32;

__device__ __forceinline__ ushort f2b(float f) {       // f32 -> bf16 (RNE)
    union { float f; unsigned int i; } v; v.f = f;
    unsigned int lsb = (v.i >> 16) & 1u;
    unsigned int r = v.i + 0x7fffu + lsb;
    return (ushort)(r >> 16);
}
__device__ __forceinline__ int cix(int v, int hi) {    // clamp index to [0, hi)
    return v < 0 ? 0 : (v >= hi ? hi - 1 : v);
}

// ---------- fused prep: zero accumulators + weight prep, block-partitioned ----------
//  blocks [0,128):   transpose+cast W1 [OBS x HID] -> Wt1 [HID x OBS] bf16
//  blocks [128,385): M2bf[i][:] = bf16(W2[i,:] @ Wl); row HID -> b2l = b2@Wl + bl
//  blocks [385,698): zero zacc / pool / cnt / degi / done
__global__ __launch_bounds__(256) void k_prep(const float* __restrict__ W1,
                                              const float* __restrict__ W2,
                                              const float* __restrict__ Wl,
                                              const float* __restrict__ b2,
                                              const float* __restrict__ bl,
                                              ushort* __restrict__ Wt1,
                                              ushort* __restrict__ M2bf,
                                              float* __restrict__ b2l,
                                              float* __restrict__ zacc,
                                              float* __restrict__ pool,
                                              float* __restrict__ cnt,
                                              int* __restrict__ degi,
                                              int* __restrict__ done) {
    int blk = blockIdx.x;
    if (blk >= 385) {
        int idx = (blk - 385) * 256 + threadIdx.x;
        if (idx < NNODES * ACTD) zacc[idx] = 0.0f;
        if (idx < NGR * ACTD) pool[idx] = 0.0f;
        if (idx < NGR) cnt[idx] = 0.0f;
        if (idx < NNODES) degi[idx] = 0;
        if (idx == 0) *done = 0;
        return;
    }
    if (blk < 128) {
        __shared__ float tile[32][33];
        int bx = (blk & 31) * 32, by = (blk >> 5) * 32;  // bx over HID, by over OBS
        int tx = threadIdx.x & 31, ty = threadIdx.x >> 5;
        #pragma unroll
        for (int i = 0; i < 32; i += 8)
            tile[ty + i][tx] = W1[(size_t)(by + ty + i) * HID + bx + tx];
        __syncthreads();
        #pragma unroll
        for (int i = 0; i < 32; i += 8)
            Wt1[(size_t)(bx + ty + i) * OBS + by + tx] = f2b(tile[tx][ty + i]);
        return;
    }
    int wvid = ((blk - 128) * 256 + (int)threadIdx.x) >> 6;
    int lane = threadIdx.x & 63;
    if (wvid > HID) return;
    const float* row = (wvid == HID) ? b2 : (W2 + (size_t)wvid * HID);
    float acc[ACTD];
    #pragma unroll
    for (int j = 0; j < ACTD; ++j) acc[j] = 0.0f;
    for (int it = 0; it < HID / 64; ++it) {
        int k = it * 64 + lane;
        float w2v = row[k];
        float4 a = *(const float4*)(Wl + (size_t)k * ACTD);
        float4 b = *(const float4*)(Wl + (size_t)k * ACTD + 4);
        acc[0] += w2v * a.x; acc[1] += w2v * a.y; acc[2] += w2v * a.z; acc[3] += w2v * a.w;
        acc[4] += w2v * b.x; acc[5] += w2v * b.y; acc[6] += w2v * b.z; acc[7] += w2v * b.w;
    }
    #pragma unroll
    for (int off = 32; off > 0; off >>= 1)
        #pragma unroll
        for (int j = 0; j < ACTD; ++j)
            acc[j] += __shfl_down(acc[j], off);
    if (lane == 0) {
        if (wvid == HID) {
            #pragma unroll
            for (int j = 0; j < ACTD; ++j) b2l[j] = acc[j] + bl[j];
        } else {
            #pragma unroll
            for (int j = 0; j < ACTD; ++j) M2bf[wvid * ACTD + j] = f2b(acc[j]);
        }
    }
}

__global__ void k_count(const int* __restrict__ dst, int* degi, int e) {
    int i = blockIdx.x * 256 + threadIdx.x;
    if (i < e) atomicAdd(&degi[cix(dst[i], NNODES)], 1);
}

// single-block scan via wave shuffles (2 barriers) -> rowptr (N+1) + cursor + dinv
__global__ __launch_bounds__(1024) void k_scan(const int* __restrict__ degi,
                                               int* rowptr, int* cursor, float* dinv) {
    __shared__ int wsum[16];
    int t = threadIdx.x, lane = t & 63, w = t >> 6;
    int base = t * 10;                                   // 10240 >= NNODES
    int local[10];
    int s = 0;
    #pragma unroll
    for (int k = 0; k < 10; ++k) {
        int i = base + k;
        int v = 0;
        if (i < NNODES) {
            v = degi[i];
            dinv[i] = rsqrtf((float)(v + 1));            // +1 self-loop
        }
        local[k] = s; s += v;
    }
    int sc = s;                                          // inclusive wave scan
    #pragma unroll
    for (int off = 1; off < 64; off <<= 1) {
        int u = __shfl_up(sc, off);
        if (lane >= off) sc += u;
    }
    if (lane == 63) wsum[w] = sc;
    __syncthreads();
    if (w == 0 && lane < 16) {
        int v = wsum[lane];
        #pragma unroll
        for (int off = 1; off < 16; off <<= 1) {
            int u = __shfl_up(v, off);
            if (lane >= off) v += u;
        }
        wsum[lane] = v;                                  // inclusive wave totals
    }
    __syncthreads();
    int excl = ((w == 0) ? 0 : wsum[w - 1]) + (sc - s);  // exclusive thread offset
    #pragma unroll
    for (int k = 0; k < 10; ++k) {
        int i = base + k;
        if (i < NNODES) { rowptr[i] = excl + local[k]; cursor[i] = excl + local[k]; }
    }
    if (t == 0) rowptr[NNODES] = wsum[15];
}

// bucket edges by dst: sorted src + coef
__global__ void k_fill(const int* __restrict__ src, const int* __restrict__ dst,
                       const float* __restrict__ dinv, int* cursor,
                       int* __restrict__ esrc, float* __restrict__ coefs, int e) {
    int i = blockIdx.x * 256 + threadIdx.x;
    if (i >= e) return;
    int s = cix(src[i], NNODES), d = cix(dst[i], NNODES);
    int pos = atomicAdd(&cursor[d], 1);
    esrc[pos] = s;
    coefs[pos] = dinv[s] * dinv[d];
}

// ---------- layer-1 aggregation: CSR gather, one wave per node ----------
// lanes 0-31 process even edges, lanes 32-63 odd edges (float4/lane = full row per half);
// cross-half shfl reduce at the end. 2 edges per load instruction -> 2x MLP, half the trips.
__global__ void k_aggx(const float* __restrict__ x, const float* __restrict__ dinv,
                       const int* __restrict__ rowptr, const int* __restrict__ esrc,
                       const float* __restrict__ coefs, ushort* __restrict__ aggbf, int n) {
    int wv = (blockIdx.x * 256 + threadIdx.x) >> 6;
    int lane = threadIdx.x & 63;
    if (wv >= n) return;
    int half = lane >> 5, c = lane & 31;
    float d = dinv[wv];
    float4 v = make_float4(0.f, 0.f, 0.f, 0.f);
    if (half == 0) {                                     // self-loop term, once
        float d2 = d * d;
        float4 xs = *(const float4*)(x + (size_t)wv * OBS + c * 4);
        v.x = xs.x * d2; v.y = xs.y * d2; v.z = xs.z * d2; v.w = xs.w * d2;
    }
    int e1 = rowptr[wv + 1];
    for (int e = rowptr[wv] + half; e < e1; e += 2) {
        int s = esrc[e];
        float cf = coefs[e];
        float4 a = *(const float4*)(x + (size_t)s * OBS + c * 4);
        v.x += a.x * cf; v.y += a.y * cf; v.z += a.z * cf; v.w += a.w * cf;
    }
    v.x += __shfl_down(v.x, 32);
    v.y += __shfl_down(v.y, 32);
    v.z += __shfl_down(v.z, 32);
    v.w += __shfl_down(v.w, 32);
    if (half == 0) {
        ushort4 o;
        o.x = f2b(v.x); o.y = f2b(v.y); o.z = f2b(v.z); o.w = f2b(v.w);
        *(ushort4*)(aggbf + (size_t)wv * OBS + c * 4) = o;
    }
}

// ---------- fused GEMM1 + relu + MFMA epilogue (@M2) -> zacc ----------
// block 256 (4 waves), tile 128x128, K=OBS=128, BK=64, async global->LDS staging.
// LDS union: As(8192h)+Bs(8192h) overlapped by stage(128x136h), + M2t(16x128h) = 38912 B
__global__ __launch_bounds__(256) void k_gemm1_fused(const ushort* __restrict__ A,
                                                     const ushort* __restrict__ Bt,
                                                     const float* __restrict__ bias,
                                                     const ushort* __restrict__ M2bf,
                                                     float* __restrict__ zacc,
                                                     int M) {
    __shared__ ushort buf[128 * 136 + 16 * 128];         // 38912 B
    ushort* As    = buf;                                 // hw [0, 8192)
    ushort* Bs    = buf + 8192;                          // hw [8192, 16384)
    ushort* stage = buf;                                 // hw [0, 17408) after K-loop
    ushort* M2t   = buf + 128 * 136;                     // hw [17408, 19456)

    const int t = threadIdx.x;
    const int bm = blockIdx.x, bn = blockIdx.y;
    const int lane = t & 63, wv = t >> 6;
    const int wm = (wv & 1) * 64, wn = (wv >> 1) * 64;
    const int l16 = lane & 15, kg = (lane >> 4) * 8;

    if (t < 128) {
        ushort4 a = *(const ushort4*)(M2bf + (size_t)(bn * 128 + t) * ACTD);
        ushort4 b = *(const ushort4*)(M2bf + (size_t)(bn * 128 + t) * ACTD + 4);
        M2t[0 * 128 + t] = a.x; M2t[1 * 128 + t] = a.y;
        M2t[2 * 128 + t] = a.z; M2t[3 * 128 + t] = a.w;
        M2t[4 * 128 + t] = b.x; M2t[5 * 128 + t] = b.y;
        M2t[6 * 128 + t] = b.z; M2t[7 * 128 + t] = b.w;
        #pragma unroll
        for (int j = 8; j < 16; ++j) M2t[j * 128 + t] = 0;
    }

    f32x4 acc[4][4];
    #pragma unroll
    for (int i = 0; i < 4; ++i)
        #pragma unroll
        for (int j = 0; j < 4; ++j)
            acc[i][j] = (f32x4){0.f, 0.f, 0.f, 0.f};

    const int rs = t >> 3;                               // 0..31
    const int cs = (t & 7) * 8;                          // hw col, 16B chunks
    #pragma unroll
    for (int kt = 0; kt < OBS; kt += 64) {
        #pragma unroll
        for (int p = 0; p < 4; ++p) {                    // 32 rows/pass
            int r = rs + p * 32;
            int gr = bm * 128 + r; if (gr >= M) gr = M - 1;   // clamp (row discarded later)
            __builtin_amdgcn_global_load_lds(
                (gl_u32*)(A + (size_t)gr * OBS + kt + cs),
                (lds_u32*)(As + r * 64 + cs), 16, 0, 0);
            int gn = bn * 128 + r;
            __builtin_amdgcn_global_load_lds(
                (gl_u32*)(Bt + (size_t)gn * OBS + kt + cs),
                (lds_u32*)(Bs + r * 64 + cs), 16, 0, 0);
        }
        __syncthreads();                                 // drains vmcnt + barrier
        #pragma unroll
        for (int k2 = 0; k2 < 64; k2 += 32) {
            bf16x8 af[4], bfr[4];
            #pragma unroll
            for (int i = 0; i < 4; ++i)
                af[i] = *(const bf16x8*)(As + (wm + i * 16 + l16) * 64 + k2 + kg);
            #pragma unroll
            for (int j = 0; j < 4; ++j)
                bfr[j] = *(const bf16x8*)(Bs + (wn + j * 16 + l16) * 64 + k2 + kg);
            #pragma unroll
            for (int i = 0; i < 4; ++i)
                #pragma unroll
                for (int j = 0; j < 4; ++j)
                    acc[i][j] = __builtin_amdgcn_mfma_f32_16x16x32_bf16(af[i], bfr[j], acc[i][j], 0, 0, 0);
        }
        __syncthreads();                                 // LDS reads done before overwrite
    }

    // relu(acc + bias) -> stage bf16; C/D layout: col=lane&15, row=(lane>>4)*4+reg
    #pragma unroll
    for (int i = 0; i < 4; ++i) {
        int rowb = wm + i * 16 + (lane >> 4) * 4;
        #pragma unroll
        for (int j = 0; j < 4; ++j) {
            int col = wn + j * 16 + l16;
            float bj = bias[bn * 128 + col];
            #pragma unroll
            for (int r = 0; r < 4; ++r)
                stage[(rowb + r) * 136 + col] = f2b(fmaxf(acc[i][j][r] + bj, 0.0f));
        }
    }
    __syncthreads();

    #pragma unroll
    for (int st = 0; st < 2; ++st) {
        int row0 = wv * 32 + st * 16;
        f32x4 z = (f32x4){0.f, 0.f, 0.f, 0.f};
        #pragma unroll
        for (int kt = 0; kt < 128; kt += 32) {
            bf16x8 a = *(const bf16x8*)(stage + (row0 + l16) * 136 + kt + kg);
            bf16x8 b = *(const bf16x8*)(M2t + l16 * 128 + kt + kg);
            z = __builtin_amdgcn_mfma_f32_16x16x32_bf16(a, b, z, 0, 0, 0);
        }
        if (l16 < ACTD) {
            int rowb = bm * 128 + row0 + (lane >> 4) * 4;
            #pragma unroll
            for (int r = 0; r < 4; ++r)
                if (rowb + r < M)
                    atomicAdd(&zacc[(size_t)(rowb + r) * ACTD + l16], z[r]);
        }
    }
}

// ---------- z-aggregation (gather) + tanh + hierarchical pool + last-block finalize ----------
// 313 blocks x 256 (32 nodes/block) -> all 256 CUs active; k_final folded in.
__global__ __launch_bounds__(256) void k_zfinal(const float* __restrict__ zacc,
                                                const float* __restrict__ dinv,
                                                const int* __restrict__ rowptr,
                                                const int* __restrict__ esrc,
                                                const float* __restrict__ coefs,
                                                const float* __restrict__ b2l,
                                                const int* __restrict__ batch,
                                                float* __restrict__ pool,
                                                float* __restrict__ cnt,
                                                int* __restrict__ done,
                                                float* __restrict__ out, int n) {
    __shared__ float part[NGR * ACTD];
    __shared__ int   partc[NGR];
    __shared__ int   lastblk;
    int t = threadIdx.x;
    part[t] = 0.0f; part[t + 256] = 0.0f;
    if (t < NGR) partc[t] = 0;
    __syncthreads();

    int idx = blockIdx.x * 256 + t;
    int i = idx >> 3, j = idx & 7;
    if (i < n) {
        float d = dinv[i];
        float v = zacc[idx] * d * d;
        int e0 = rowptr[i], e1 = rowptr[i + 1];
        for (int e = e0; e < e1; ++e)
            v += coefs[e] * zacc[(size_t)esrc[e] * ACTD + j];
        float tz = tanhf(v + b2l[j]);
        int g = cix(batch[i], NGR);
        atomicAdd(&part[g * ACTD + j], tz);
        if (j == 0) atomicAdd(&partc[g], 1);
    }
    __syncthreads();

    int i0 = (blockIdx.x * 256) >> 3;                    // always < n for this grid
    int i1 = (blockIdx.x * 256 + 255) >> 3;
    if (i1 >= n) i1 = n - 1;
    int g0 = cix(batch[i0], NGR), g1 = cix(batch[i1], NGR);
    int ng = g1 - g0 + 1;                                // sorted batch => contiguous
    for (int u = t; u < ng * ACTD; u += 256)
        atomicAdd(&pool[g0 * ACTD + u], part[g0 * ACTD + u]);
    for (int u = t; u < ng; u += 256) {
        int c = partc[g0 + u];
        if (c) atomicAdd(&cnt[g0 + u], (float)c);
    }

    // completion counter: last block computes the final means (replaces k_final)
    __threadfence();
    __syncthreads();
    if (t == 0) {
        unsigned old = __hip_atomic_fetch_add((unsigned int*)done, 1u,
                                              __ATOMIC_ACQ_REL, __HIP_MEMORY_SCOPE_AGENT);
        lastblk = (old == (unsigned)(gridDim.x - 1));
    }
    __syncthreads();
    if (lastblk) {
        for (int u = t; u < NGR * ACTD; u += 256) {
            float p = __hip_atomic_load(&pool[u], __ATOMIC_RELAXED, __HIP_MEMORY_SCOPE_AGENT);
            float c = __hip_atomic_load(&cnt[u >> 3], __ATOMIC_RELAXED, __HIP_MEMORY_SCOPE_AGENT);
            out[u] = p / fmaxf(c, 1.0f);
        }
    }
}

// ---------- launch ----------
extern "C" void kernel_launch(void* const* d_in, const int* in_sizes, int n_in,
                              void* d_out, int out_size, void* d_ws, size_t ws_size,
                              hipStream_t stream) {
    const float* x   = (const float*)d_in[0];
    const int*   ei  = (const int*)d_in[1];
    const int*   bat = (const int*)d_in[2];
    const float* W1  = (const float*)d_in[3];
    const float* b1  = (const float*)d_in[4];
    const float* W2  = (const float*)d_in[5];
    const float* b2v = (const float*)d_in[6];
    const float* Wl  = (const float*)d_in[7];
    const float* bl  = (const float*)d_in[8];
    float* out = (float*)d_out;

    const int N = NNODES, E = NEDGES;
    const int* src = ei;
    const int* dst = ei + E;

    // workspace layout — ~4.3 MB total (all offsets multiples of 256 B)
    char* ws = (char*)d_ws;
    size_t off = 0;
    float*  pool   = (float*)(ws + off); off += 2048;
    float*  cnt    = (float*)(ws + off); off += 256;
    float*  dinv   = (float*)(ws + off); off += 40192;                   // N f32
    int*    degi   = (int*)(ws + off);   off += 40192;                   // N i32
    int*    rowptr = (int*)(ws + off);   off += 40448;                   // N+1 i32
    int*    cursor = (int*)(ws + off);   off += 40192;                   // N i32
    int*    esrc   = (int*)(ws + off);   off += (size_t)E * 4;           // 320000
    float*  coefs  = (float*)(ws + off); off += (size_t)E * 4;           // 320000
    float*  b2l    = (float*)(ws + off); off += 256;
    ushort* M2bf   = (ushort*)(ws + off); off += (size_t)HID * ACTD * 2; // 16384
    ushort* Wt1    = (ushort*)(ws + off); off += (size_t)HID * OBS * 2;  // 262144
    float*  zacc   = (float*)(ws + off); off += (size_t)N * ACTD * 4;    // 320000
    ushort* aggbf  = (ushort*)(ws + off); off += (size_t)N * OBS * 2;    // 2560000
    int*    done   = (int*)(ws + off);   off += 256;                     // 1 i32

    // 1. fused zero + weight prep
    k_prep<<<698, 256, 0, stream>>>(W1, W2, Wl, b2v, bl, Wt1, M2bf, b2l,
                                    zacc, pool, cnt, degi, done);
    // 2-4. degree, scan(+dinv), CSR fill (plain launches — grid.sync costs ~36us each, measured R3)
    k_count<<<(E + 255) / 256, 256, 0, stream>>>(dst, degi, E);
    k_scan<<<1, 1024, 0, stream>>>(degi, rowptr, cursor, dinv);
    k_fill<<<(E + 255) / 256, 256, 0, stream>>>(src, dst, dinv, cursor, esrc, coefs, E);

    // 5. layer-1 aggregation (gather) -> bf16
    k_aggx<<<(N * 64 + 255) / 256, 256, 0, stream>>>(x, dinv, rowptr, esrc, coefs, aggbf, N);

    // 6. fused GEMM1 + relu + @M2 -> zacc
    k_gemm1_fused<<<dim3((N + 127) / 128, HID / 128), 256, 0, stream>>>(
        aggbf, Wt1, b1, M2bf, zacc, N);

    // 7. z-aggregation (gather) + tanh + pool + finalize (k_final folded in)
    k_zfinal<<<(N * ACTD + 255) / 256, 256, 0, stream>>>(
        zacc, dinv, rowptr, esrc, coefs, b2l, bat, pool, cnt, done, out, N);
}

// Round 5
// 133.809 us; speedup vs baseline: 2.2735x; 1.1635x over previous
//
#include <hip/hip_runtime.h>
#include <hip/hip_bf16.h>

// ---------- constants (problem-fixed) ----------
#define NNODES 10000
#define NEDGES 80000
#define OBS    128
#define HID    1024
#define ACTD   8
#define NGR    64

typedef __bf16 bf16x8 __attribute__((ext_vector_type(8)));
typedef float  f32x4  __attribute__((ext_vector_type(4)));
typedef const __attribute__((address_space(1))) unsigned int gl_u32;
typedef __attribute__((address_space(3))) unsigned int lds_u32;

__device__ __forceinline__ ushort f2b(float f) {       // f32 -> bf16 (RNE)
    union { float f; unsigned int i; } v; v.f = f;
    unsigned int lsb = (v.i >> 16) & 1u;
    unsigned int r = v.i + 0x7fffu + lsb;
    return (ushort)(r >> 16);
}
__device__ __forceinline__ int cix(int v, int hi) {    // clamp index to [0, hi)
    return v < 0 ? 0 : (v >= hi ? hi - 1 : v);
}

// ---------- fused prep: zero accumulators + weight prep, block-partitioned ----------
//  blocks [0,128):   transpose+cast W1 [OBS x HID] -> Wt1 [HID x OBS] bf16
//  blocks [128,385): M2bf[i][:] = bf16(W2[i,:] @ Wl); row HID -> b2l = b2@Wl + bl
//  blocks [385,698): zero zacc / pool / cnt / degi
__global__ __launch_bounds__(256) void k_prep(const float* __restrict__ W1,
                                              const float* __restrict__ W2,
                                              const float* __restrict__ Wl,
                                              const float* __restrict__ b2,
                                              const float* __restrict__ bl,
                                              ushort* __restrict__ Wt1,
                                              ushort* __restrict__ M2bf,
                                              float* __restrict__ b2l,
                                              float* __restrict__ zacc,
                                              float* __restrict__ pool,
                                              float* __restrict__ cnt,
                                              int* __restrict__ degi) {
    int blk = blockIdx.x;
    if (blk >= 385) {
        int idx = (blk - 385) * 256 + threadIdx.x;
        if (idx < NNODES * ACTD) zacc[idx] = 0.0f;
        if (idx < NGR * ACTD) pool[idx] = 0.0f;
        if (idx < NGR) cnt[idx] = 0.0f;
        if (idx < NNODES) degi[idx] = 0;
        return;
    }
    if (blk < 128) {
        __shared__ float tile[32][33];
        int bx = (blk & 31) * 32, by = (blk >> 5) * 32;  // bx over HID, by over OBS
        int tx = threadIdx.x & 31, ty = threadIdx.x >> 5;
        #pragma unroll
        for (int i = 0; i < 32; i += 8)
            tile[ty + i][tx] = W1[(size_t)(by + ty + i) * HID + bx + tx];
        __syncthreads();
        #pragma unroll
        for (int i = 0; i < 32; i += 8)
            Wt1[(size_t)(bx + ty + i) * OBS + by + tx] = f2b(tile[tx][ty + i]);
        return;
    }
    int wvid = ((blk - 128) * 256 + (int)threadIdx.x) >> 6;
    int lane = threadIdx.x & 63;
    if (wvid > HID) return;
    const float* row = (wvid == HID) ? b2 : (W2 + (size_t)wvid * HID);
    float acc[ACTD];
    #pragma unroll
    for (int j = 0; j < ACTD; ++j) acc[j] = 0.0f;
    for (int it = 0; it < HID / 64; ++it) {
        int k = it * 64 + lane;
        float w2v = row[k];
        float4 a = *(const float4*)(Wl + (size_t)k * ACTD);
        float4 b = *(const float4*)(Wl + (size_t)k * ACTD + 4);
        acc[0] += w2v * a.x; acc[1] += w2v * a.y; acc[2] += w2v * a.z; acc[3] += w2v * a.w;
        acc[4] += w2v * b.x; acc[5] += w2v * b.y; acc[6] += w2v * b.z; acc[7] += w2v * b.w;
    }
    #pragma unroll
    for (int off = 32; off > 0; off >>= 1)
        #pragma unroll
        for (int j = 0; j < ACTD; ++j)
            acc[j] += __shfl_down(acc[j], off);
    if (lane == 0) {
        if (wvid == HID) {
            #pragma unroll
            for (int j = 0; j < ACTD; ++j) b2l[j] = acc[j] + bl[j];
        } else {
            #pragma unroll
            for (int j = 0; j < ACTD; ++j) M2bf[wvid * ACTD + j] = f2b(acc[j]);
        }
    }
}

__global__ void k_count(const int* __restrict__ dst, int* degi, int e) {
    int i = blockIdx.x * 256 + threadIdx.x;
    if (i < e) atomicAdd(&degi[cix(dst[i], NNODES)], 1);
}

// single-block scan via wave shuffles (2 barriers) -> rowptr (N+1) + cursor + dinv
__global__ __launch_bounds__(1024) void k_scan(const int* __restrict__ degi,
                                               int* rowptr, int* cursor, float* dinv) {
    __shared__ int wsum[16];
    int t = threadIdx.x, lane = t & 63, w = t >> 6;
    int base = t * 10;                                   // 10240 >= NNODES
    int local[10];
    int s = 0;
    #pragma unroll
    for (int k = 0; k < 10; ++k) {
        int i = base + k;
        int v = 0;
        if (i < NNODES) {
            v = degi[i];
            dinv[i] = rsqrtf((float)(v + 1));            // +1 self-loop
        }
        local[k] = s; s += v;
    }
    int sc = s;                                          // inclusive wave scan
    #pragma unroll
    for (int off = 1; off < 64; off <<= 1) {
        int u = __shfl_up(sc, off);
        if (lane >= off) sc += u;
    }
    if (lane == 63) wsum[w] = sc;
    __syncthreads();
    if (w == 0 && lane < 16) {
        int v = wsum[lane];
        #pragma unroll
        for (int off = 1; off < 16; off <<= 1) {
            int u = __shfl_up(v, off);
            if (lane >= off) v += u;
        }
        wsum[lane] = v;                                  // inclusive wave totals
    }
    __syncthreads();
    int excl = ((w == 0) ? 0 : wsum[w - 1]) + (sc - s);  // exclusive thread offset
    #pragma unroll
    for (int k = 0; k < 10; ++k) {
        int i = base + k;
        if (i < NNODES) { rowptr[i] = excl + local[k]; cursor[i] = excl + local[k]; }
    }
    if (t == 0) rowptr[NNODES] = wsum[15];
}

// bucket edges by dst: sorted src + coef
__global__ void k_fill(const int* __restrict__ src, const int* __restrict__ dst,
                       const float* __restrict__ dinv, int* cursor,
                       int* __restrict__ esrc, float* __restrict__ coefs, int e) {
    int i = blockIdx.x * 256 + threadIdx.x;
    if (i >= e) return;
    int s = cix(src[i], NNODES), d = cix(dst[i], NNODES);
    int pos = atomicAdd(&cursor[d], 1);
    esrc[pos] = s;
    coefs[pos] = dinv[s] * dinv[d];
}

// ---------- layer-1 aggregation: CSR gather, one wave per node ----------
// lanes 0-31 process even edges, lanes 32-63 odd edges (float4/lane = full row per half);
// cross-half shfl reduce at the end. 2 edges per load instruction -> half the trips.
__global__ void k_aggx(const float* __restrict__ x, const float* __restrict__ dinv,
                       const int* __restrict__ rowptr, const int* __restrict__ esrc,
                       const float* __restrict__ coefs, ushort* __restrict__ aggbf, int n) {
    int wv = (blockIdx.x * 256 + threadIdx.x) >> 6;
    int lane = threadIdx.x & 63;
    if (wv >= n) return;
    int half = lane >> 5, c = lane & 31;
    float d = dinv[wv];
    float4 v = make_float4(0.f, 0.f, 0.f, 0.f);
    if (half == 0) {                                     // self-loop term, once
        float d2 = d * d;
        float4 xs = *(const float4*)(x + (size_t)wv * OBS + c * 4);
        v.x = xs.x * d2; v.y = xs.y * d2; v.z = xs.z * d2; v.w = xs.w * d2;
    }
    int e1 = rowptr[wv + 1];
    for (int e = rowptr[wv] + half; e < e1; e += 2) {
        int s = esrc[e];
        float cf = coefs[e];
        float4 a = *(const float4*)(x + (size_t)s * OBS + c * 4);
        v.x += a.x * cf; v.y += a.y * cf; v.z += a.z * cf; v.w += a.w * cf;
    }
    v.x += __shfl_down(v.x, 32);
    v.y += __shfl_down(v.y, 32);
    v.z += __shfl_down(v.z, 32);
    v.w += __shfl_down(v.w, 32);
    if (half == 0) {
        ushort4 o;
        o.x = f2b(v.x); o.y = f2b(v.y); o.z = f2b(v.z); o.w = f2b(v.w);
        *(ushort4*)(aggbf + (size_t)wv * OBS + c * 4) = o;
    }
}

// ---------- fused GEMM1 + relu + MFMA epilogue (@M2) -> zacc ----------
// block 256 (4 waves), tile 128x128, K=OBS=128, BK=64, async global->LDS staging.
// LDS union: As(8192h)+Bs(8192h) overlapped by stage(128x136h), + M2t(16x128h) = 38912 B
__global__ __launch_bounds__(256) void k_gemm1_fused(const ushort* __restrict__ A,
                                                     const ushort* __restrict__ Bt,
                                                     const float* __restrict__ bias,
                                                     const ushort* __restrict__ M2bf,
                                                     float* __restrict__ zacc,
                                                     int M) {
    __shared__ ushort buf[128 * 136 + 16 * 128];         // 38912 B
    ushort* As    = buf;                                 // hw [0, 8192)
    ushort* Bs    = buf + 8192;                          // hw [8192, 16384)
    ushort* stage = buf;                                 // hw [0, 17408) after K-loop
    ushort* M2t   = buf + 128 * 136;                     // hw [17408, 19456)

    const int t = threadIdx.x;
    const int bm = blockIdx.x, bn = blockIdx.y;
    const int lane = t & 63, wv = t >> 6;
    const int wm = (wv & 1) * 64, wn = (wv >> 1) * 64;
    const int l16 = lane & 15, kg = (lane >> 4) * 8;

    if (t < 128) {
        ushort4 a = *(const ushort4*)(M2bf + (size_t)(bn * 128 + t) * ACTD);
        ushort4 b = *(const ushort4*)(M2bf + (size_t)(bn * 128 + t) * ACTD + 4);
        M2t[0 * 128 + t] = a.x; M2t[1 * 128 + t] = a.y;
        M2t[2 * 128 + t] = a.z; M2t[3 * 128 + t] = a.w;
        M2t[4 * 128 + t] = b.x; M2t[5 * 128 + t] = b.y;
        M2t[6 * 128 + t] = b.z; M2t[7 * 128 + t] = b.w;
        #pragma unroll
        for (int j = 8; j < 16; ++j) M2t[j * 128 + t] = 0;
    }

    f32x4 acc[4][4];
    #pragma unroll
    for (int i = 0; i < 4; ++i)
        #pragma unroll
        for (int j = 0; j < 4; ++j)
            acc[i][j] = (f32x4){0.f, 0.f, 0.f, 0.f};

    const int rs = t >> 3;                               // 0..31
    const int cs = (t & 7) * 8;                          // hw col, 16B chunks
    #pragma unroll
    for (int kt = 0; kt < OBS; kt += 64) {
        #pragma unroll
        for (int p = 0; p < 4; ++p) {                    // 32 rows/pass
            int r = rs + p * 32;
            int gr = bm * 128 + r; if (gr >= M) gr = M - 1;   // clamp (row discarded later)
            __builtin_amdgcn_global_load_lds(
                (gl_u32*)(A + (size_t)gr * OBS + kt + cs),
                (lds_u32*)(As + r * 64 + cs), 16, 0, 0);
            int gn = bn * 128 + r;
            __builtin_amdgcn_global_load_lds(
                (gl_u32*)(Bt + (size_t)gn * OBS + kt + cs),
                (lds_u32*)(Bs + r * 64 + cs), 16, 0, 0);
        }
        __syncthreads();                                 // drains vmcnt + barrier
        #pragma unroll
        for (int k2 = 0; k2 < 64; k2 += 32) {
            bf16x8 af[4], bfr[4];
            #pragma unroll
            for (int i = 0; i < 4; ++i)
                af[i] = *(const bf16x8*)(As + (wm + i * 16 + l16) * 64 + k2 + kg);
            #pragma unroll
            for (int j = 0; j < 4; ++j)
                bfr[j] = *(const bf16x8*)(Bs + (wn + j * 16 + l16) * 64 + k2 + kg);
            #pragma unroll
            for (int i = 0; i < 4; ++i)
                #pragma unroll
                for (int j = 0; j < 4; ++j)
                    acc[i][j] = __builtin_amdgcn_mfma_f32_16x16x32_bf16(af[i], bfr[j], acc[i][j], 0, 0, 0);
        }
        __syncthreads();                                 // LDS reads done before overwrite
    }

    // relu(acc + bias) -> stage bf16; C/D layout: col=lane&15, row=(lane>>4)*4+reg
    #pragma unroll
    for (int i = 0; i < 4; ++i) {
        int rowb = wm + i * 16 + (lane >> 4) * 4;
        #pragma unroll
        for (int j = 0; j < 4; ++j) {
            int col = wn + j * 16 + l16;
            float bj = bias[bn * 128 + col];
            #pragma unroll
            for (int r = 0; r < 4; ++r)
                stage[(rowb + r) * 136 + col] = f2b(fmaxf(acc[i][j][r] + bj, 0.0f));
        }
    }
    __syncthreads();

    #pragma unroll
    for (int st = 0; st < 2; ++st) {
        int row0 = wv * 32 + st * 16;
        f32x4 z = (f32x4){0.f, 0.f, 0.f, 0.f};
        #pragma unroll
        for (int kt = 0; kt < 128; kt += 32) {
            bf16x8 a = *(const bf16x8*)(stage + (row0 + l16) * 136 + kt + kg);
            bf16x8 b = *(const bf16x8*)(M2t + l16 * 128 + kt + kg);
            z = __builtin_amdgcn_mfma_f32_16x16x32_bf16(a, b, z, 0, 0, 0);
        }
        if (l16 < ACTD) {
            int rowb = bm * 128 + row0 + (lane >> 4) * 4;
            #pragma unroll
            for (int r = 0; r < 4; ++r)
                if (rowb + r < M)
                    atomicAdd(&zacc[(size_t)(rowb + r) * ACTD + l16], z[r]);
        }
    }
}

// ---------- z-aggregation (gather) + tanh + hierarchical pool ----------
__global__ __launch_bounds__(1024) void k_zfinal(const float* __restrict__ zacc,
                                                 const float* __restrict__ dinv,
                                                 const int* __restrict__ rowptr,
                                                 const int* __restrict__ esrc,
                                                 const float* __restrict__ coefs,
                                                 const float* __restrict__ b2l,
                                                 const int* __restrict__ batch,
                                                 float* __restrict__ pool,
                                                 float* __restrict__ cnt, int n) {
    __shared__ float part[NGR * ACTD];
    __shared__ int   partc[NGR];
    int t = threadIdx.x;
    if (t < NGR * ACTD) part[t] = 0.0f;
    if (t < NGR) partc[t] = 0;
    __syncthreads();

    int idx = blockIdx.x * 1024 + t;
    int i = idx >> 3, j = idx & 7;
    if (i < n) {
        float d = dinv[i];
        float v = zacc[idx] * d * d;
        int e0 = rowptr[i], e1 = rowptr[i + 1];
        for (int e = e0; e < e1; ++e)
            v += coefs[e] * zacc[(size_t)esrc[e] * ACTD + j];
        float tz = tanhf(v + b2l[j]);
        int g = cix(batch[i], NGR);
        atomicAdd(&part[g * ACTD + j], tz);
        if (j == 0) atomicAdd(&partc[g], 1);
    }
    __syncthreads();

    int i0 = (blockIdx.x * 1024) >> 3;
    int i1 = (blockIdx.x * 1024 + 1023) >> 3;
    if (i0 >= n) return;
    if (i1 >= n) i1 = n - 1;
    int g0 = cix(batch[i0], NGR), g1 = cix(batch[i1], NGR);
    int ng = g1 - g0 + 1;                                // sorted batch => contiguous
    if (t < ng * ACTD)
        atomicAdd(&pool[g0 * ACTD + t], part[g0 * ACTD + t]);
    if (t < ng) {
        int c = partc[g0 + t];
        if (c) atomicAdd(&cnt[g0 + t], (float)c);
    }
}

__global__ void k_final(const float* __restrict__ pool, const float* __restrict__ cnt,
                        float* __restrict__ out, int total) {
    int i = blockIdx.x * 256 + threadIdx.x;
    if (i < total) out[i] = pool[i] / fmaxf(cnt[i >> 3], 1.0f);
}

// ---------- launch ----------
extern "C" void kernel_launch(void* const* d_in, const int* in_sizes, int n_in,
                              void* d_out, int out_size, void* d_ws, size_t ws_size,
                              hipStream_t stream) {
    const float* x   = (const float*)d_in[0];
    const int*   ei  = (const int*)d_in[1];
    const int*   bat = (const int*)d_in[2];
    const float* W1  = (const float*)d_in[3];
    const float* b1  = (const float*)d_in[4];
    const float* W2  = (const float*)d_in[5];
    const float* b2v = (const float*)d_in[6];
    const float* Wl  = (const float*)d_in[7];
    const float* bl  = (const float*)d_in[8];
    float* out = (float*)d_out;

    const int N = NNODES, E = NEDGES;
    const int* src = ei;
    const int* dst = ei + E;

    // workspace layout — ~4.3 MB total (all offsets multiples of 256 B)
    char* ws = (char*)d_ws;
    size_t off = 0;
    float*  pool   = (float*)(ws + off); off += 2048;
    float*  cnt    = (float*)(ws + off); off += 256;
    float*  dinv   = (float*)(ws + off); off += 40192;                   // N f32
    int*    degi   = (int*)(ws + off);   off += 40192;                   // N i32
    int*    rowptr = (int*)(ws + off);   off += 40448;                   // N+1 i32
    int*    cursor = (int*)(ws + off);   off += 40192;                   // N i32
    int*    esrc   = (int*)(ws + off);   off += (size_t)E * 4;           // 320000
    float*  coefs  = (float*)(ws + off); off += (size_t)E * 4;           // 320000
    float*  b2l    = (float*)(ws + off); off += 256;
    ushort* M2bf   = (ushort*)(ws + off); off += (size_t)HID * ACTD * 2; // 16384
    ushort* Wt1    = (ushort*)(ws + off); off += (size_t)HID * OBS * 2;  // 262144
    float*  zacc   = (float*)(ws + off); off += (size_t)N * ACTD * 4;    // 320000
    ushort* aggbf  = (ushort*)(ws + off); off += (size_t)N * OBS * 2;    // 2560000

    // 1. fused zero + weight prep
    k_prep<<<698, 256, 0, stream>>>(W1, W2, Wl, b2v, bl, Wt1, M2bf, b2l,
                                    zacc, pool, cnt, degi);
    // 2-4. degree, scan(+dinv), CSR fill
    k_count<<<(E + 255) / 256, 256, 0, stream>>>(dst, degi, E);
    k_scan<<<1, 1024, 0, stream>>>(degi, rowptr, cursor, dinv);
    k_fill<<<(E + 255) / 256, 256, 0, stream>>>(src, dst, dinv, cursor, esrc, coefs, E);

    // 5. layer-1 aggregation (gather) -> bf16  [half-wave float4 variant under A/B test]
    k_aggx<<<(N * 64 + 255) / 256, 256, 0, stream>>>(x, dinv, rowptr, esrc, coefs, aggbf, N);

    // 6. fused GEMM1 + relu + @M2 -> zacc
    k_gemm1_fused<<<dim3((N + 127) / 128, HID / 128), 256, 0, stream>>>(
        aggbf, Wt1, b1, M2bf, zacc, N);

    // 7. z-aggregation (gather) + tanh + hierarchical pool, finalize
    k_zfinal<<<(N * ACTD + 1023) / 1024, 1024, 0, stream>>>(
        zacc, dinv, rowptr, esrc, coefs, b2l, bat, pool, cnt, N);
    k_final<<<2, 256, 0, stream>>>(pool, cnt, out, NGR * ACTD);
}

// Round 7
// 132.505 us; speedup vs baseline: 2.2959x; 1.0098x over previous
//
#include <hip/hip_runtime.h>
#include <hip/hip_bf16.h>

// ---------- constants (problem-fixed) ----------
#define NNODES 10000
#define NEDGES 80000
#define OBS    128
#define HID    1024
#define ACTD   8
#define NGR    64

typedef __bf16 bf16x8 __attribute__((ext_vector_type(8)));
typedef float  f32x4  __attribute__((ext_vector_type(4)));
typedef ushort us8    __attribute__((ext_vector_type(8)));
typedef const __attribute__((address_space(1))) unsigned int gl_u32;
typedef __attribute__((address_space(3))) unsigned int lds_u32;

__device__ __forceinline__ ushort f2b(float f) {       // f32 -> bf16 (RNE)
    union { float f; unsigned int i; } v; v.f = f;
    unsigned int lsb = (v.i >> 16) & 1u;
    unsigned int r = v.i + 0x7fffu + lsb;
    return (ushort)(r >> 16);
}
__device__ __forceinline__ int cix(int v, int hi) {    // clamp index to [0, hi)
    return v < 0 ? 0 : (v >= hi ? hi - 1 : v);
}

// ---------- fused prep: zero accumulators + weight prep, block-partitioned ----------
//  blocks [0,128):   transpose+cast W1 [OBS x HID] -> Wt1 [HID x OBS] bf16
//  blocks [128,385): M2bf[i][:] = bf16(W2[i,:] @ Wl); row HID -> b2l = b2@Wl + bl
//  blocks [385,698): zero zacc / pool / cnt / degi
__global__ __launch_bounds__(256) void k_prep(const float* __restrict__ W1,
                                              const float* __restrict__ W2,
                                              const float* __restrict__ Wl,
                                              const float* __restrict__ b2,
                                              const float* __restrict__ bl,
                                              ushort* __restrict__ Wt1,
                                              ushort* __restrict__ M2bf,
                                              float* __restrict__ b2l,
                                              float* __restrict__ zacc,
                                              float* __restrict__ pool,
                                              float* __restrict__ cnt,
                                              int* __restrict__ degi) {
    int blk = blockIdx.x;
    if (blk >= 385) {
        int idx = (blk - 385) * 256 + threadIdx.x;
        if (idx < NNODES * ACTD) zacc[idx] = 0.0f;
        if (idx < NGR * ACTD) pool[idx] = 0.0f;
        if (idx < NGR) cnt[idx] = 0.0f;
        if (idx < NNODES) degi[idx] = 0;
        return;
    }
    if (blk < 128) {
        __shared__ float tile[32][33];
        int bx = (blk & 31) * 32, by = (blk >> 5) * 32;  // bx over HID, by over OBS
        int tx = threadIdx.x & 31, ty = threadIdx.x >> 5;
        #pragma unroll
        for (int i = 0; i < 32; i += 8)
            tile[ty + i][tx] = W1[(size_t)(by + ty + i) * HID + bx + tx];
        __syncthreads();
        #pragma unroll
        for (int i = 0; i < 32; i += 8)
            Wt1[(size_t)(bx + ty + i) * OBS + by + tx] = f2b(tile[tx][ty + i]);
        return;
    }
    int wvid = ((blk - 128) * 256 + (int)threadIdx.x) >> 6;
    int lane = threadIdx.x & 63;
    if (wvid > HID) return;
    const float* row = (wvid == HID) ? b2 : (W2 + (size_t)wvid * HID);
    float acc[ACTD];
    #pragma unroll
    for (int j = 0; j < ACTD; ++j) acc[j] = 0.0f;
    for (int it = 0; it < HID / 64; ++it) {
        int k = it * 64 + lane;
        float w2v = row[k];
        float4 a = *(const float4*)(Wl + (size_t)k * ACTD);
        float4 b = *(const float4*)(Wl + (size_t)k * ACTD + 4);
        acc[0] += w2v * a.x; acc[1] += w2v * a.y; acc[2] += w2v * a.z; acc[3] += w2v * a.w;
        acc[4] += w2v * b.x; acc[5] += w2v * b.y; acc[6] += w2v * b.z; acc[7] += w2v * b.w;
    }
    #pragma unroll
    for (int off = 32; off > 0; off >>= 1)
        #pragma unroll
        for (int j = 0; j < ACTD; ++j)
            acc[j] += __shfl_down(acc[j], off);
    if (lane == 0) {
        if (wvid == HID) {
            #pragma unroll
            for (int j = 0; j < ACTD; ++j) b2l[j] = acc[j] + bl[j];
        } else {
            #pragma unroll
            for (int j = 0; j < ACTD; ++j) M2bf[wvid * ACTD + j] = f2b(acc[j]);
        }
    }
}

// degree count + L3 warm of x (rule-17 keepalive): x read here streams 5 MB into
// the die-level L3 so k_aggx's random 512 B gathers hit L3 (~300cy) not HBM (~900cy).
__global__ void k_count(const int* __restrict__ dst, int* degi,
                        const float* __restrict__ xw, int e) {
    int i = blockIdx.x * 256 + threadIdx.x;
    if (i < e) atomicAdd(&degi[cix(dst[i], NNODES)], 1);
    float wacc = 0.0f;
    int stride = gridDim.x * 256;
    for (int k = i; k < NNODES * OBS / 4; k += stride) {
        float4 v = *((const float4*)xw + k);
        wacc += v.x + v.y + v.z + v.w;
    }
    asm volatile("" :: "v"(wacc));                       // keep loads alive, no store
}

// single-block scan via wave shuffles (2 barriers) -> rowptr (N+1) + cursor + dinv
__global__ __launch_bounds__(1024) void k_scan(const int* __restrict__ degi,
                                               int* rowptr, int* cursor, float* dinv) {
    __shared__ int wsum[16];
    int t = threadIdx.x, lane = t & 63, w = t >> 6;
    int base = t * 10;                                   // 10240 >= NNODES
    int local[10];
    int s = 0;
    #pragma unroll
    for (int k = 0; k < 10; ++k) {
        int i = base + k;
        int v = 0;
        if (i < NNODES) {
            v = degi[i];
            dinv[i] = rsqrtf((float)(v + 1));            // +1 self-loop
        }
        local[k] = s; s += v;
    }
    int sc = s;                                          // inclusive wave scan
    #pragma unroll
    for (int off = 1; off < 64; off <<= 1) {
        int u = __shfl_up(sc, off);
        if (lane >= off) sc += u;
    }
    if (lane == 63) wsum[w] = sc;
    __syncthreads();
    if (w == 0 && lane < 16) {
        int v = wsum[lane];
        #pragma unroll
        for (int off = 1; off < 16; off <<= 1) {
            int u = __shfl_up(v, off);
            if (lane >= off) v += u;
        }
        wsum[lane] = v;                                  // inclusive wave totals
    }
    __syncthreads();
    int excl = ((w == 0) ? 0 : wsum[w - 1]) + (sc - s);  // exclusive thread offset
    #pragma unroll
    for (int k = 0; k < 10; ++k) {
        int i = base + k;
        if (i < NNODES) { rowptr[i] = excl + local[k]; cursor[i] = excl + local[k]; }
    }
    if (t == 0) rowptr[NNODES] = wsum[15];
}

// bucket edges by dst: sorted src + coef
__global__ void k_fill(const int* __restrict__ src, const int* __restrict__ dst,
                       const float* __restrict__ dinv, int* cursor,
                       int* __restrict__ esrc, float* __restrict__ coefs, int e) {
    int i = blockIdx.x * 256 + threadIdx.x;
    if (i >= e) return;
    int s = cix(src[i], NNODES), d = cix(dst[i], NNODES);
    int pos = atomicAdd(&cursor[d], 1);
    esrc[pos] = s;
    coefs[pos] = dinv[s] * dinv[d];
}

// ---------- layer-1 aggregation: CSR gather, one wave per node, quarter-wave/edge ----------
// 16 lanes x 32 B (float8) cover a 512 B row; 4 quarters process 4 edges in flight
// per iteration -> 2x the MLP and half the trips of the half-wave version.
__global__ void k_aggx(const float* __restrict__ x, const float* __restrict__ dinv,
                       const int* __restrict__ rowptr, const int* __restrict__ esrc,
                       const float* __restrict__ coefs, ushort* __restrict__ aggbf, int n) {
    int wv = (blockIdx.x * 256 + threadIdx.x) >> 6;
    int lane = threadIdx.x & 63;
    if (wv >= n) return;
    int q = lane >> 4, c = lane & 15;                    // quarter, col-chunk (8 f32)
    float4 v0 = make_float4(0.f, 0.f, 0.f, 0.f), v1 = v0;
    if (q == 0) {                                        // self-loop term, once
        float d = dinv[wv], d2 = d * d;
        const float* xs = x + (size_t)wv * OBS + c * 8;
        float4 a0 = *(const float4*)(xs);
        float4 a1 = *(const float4*)(xs + 4);
        v0.x = a0.x * d2; v0.y = a0.y * d2; v0.z = a0.z * d2; v0.w = a0.w * d2;
        v1.x = a1.x * d2; v1.y = a1.y * d2; v1.z = a1.z * d2; v1.w = a1.w * d2;
    }
    int e1 = rowptr[wv + 1];
    for (int e = rowptr[wv] + q; e < e1; e += 4) {
        int s = esrc[e];
        float cf = coefs[e];
        const float* xs = x + (size_t)s * OBS + c * 8;
        float4 a0 = *(const float4*)(xs);
        float4 a1 = *(const float4*)(xs + 4);
        v0.x += a0.x * cf; v0.y += a0.y * cf; v0.z += a0.z * cf; v0.w += a0.w * cf;
        v1.x += a1.x * cf; v1.y += a1.y * cf; v1.z += a1.z * cf; v1.w += a1.w * cf;
    }
    #pragma unroll
    for (int off = 16; off <= 32; off <<= 1) {           // butterfly across quarters
        v0.x += __shfl_xor(v0.x, off); v0.y += __shfl_xor(v0.y, off);
        v0.z += __shfl_xor(v0.z, off); v0.w += __shfl_xor(v0.w, off);
        v1.x += __shfl_xor(v1.x, off); v1.y += __shfl_xor(v1.y, off);
        v1.z += __shfl_xor(v1.z, off); v1.w += __shfl_xor(v1.w, off);
    }
    if (q == 0) {
        us8 o;
        o[0] = f2b(v0.x); o[1] = f2b(v0.y); o[2] = f2b(v0.z); o[3] = f2b(v0.w);
        o[4] = f2b(v1.x); o[5] = f2b(v1.y); o[6] = f2b(v1.z); o[7] = f2b(v1.w);
        *(us8*)(aggbf + (size_t)wv * OBS + c * 8) = o;   // 16 B store, 16 lanes = row
    }
}

// ---------- fused GEMM1 + relu + MFMA epilogue (@M2) -> zacc ----------
// block 256 (4 waves), tile 128x128, K=OBS=128, BK=64, async global->LDS staging.
// LDS union: As(8192h)+Bs(8192h) overlapped by stage(128x136h), + M2t(16x128h) = 38912 B
__global__ __launch_bounds__(256) void k_gemm1_fused(const ushort* __restrict__ A,
                                                     const ushort* __restrict__ Bt,
                                                     const float* __restrict__ bias,
                                                     const ushort* __restrict__ M2bf,
                                                     float* __restrict__ zacc,
                                                     int M) {
    __shared__ ushort buf[128 * 136 + 16 * 128];         // 38912 B
    ushort* As    = buf;                                 // hw [0, 8192)
    ushort* Bs    = buf + 8192;                          // hw [8192, 16384)
    ushort* stage = buf;                                 // hw [0, 17408) after K-loop
    ushort* M2t   = buf + 128 * 136;                     // hw [17408, 19456)

    const int t = threadIdx.x;
    const int bm = blockIdx.x, bn = blockIdx.y;
    const int lane = t & 63, wv = t >> 6;
    const int wm = (wv & 1) * 64, wn = (wv >> 1) * 64;
    const int l16 = lane & 15, kg = (lane >> 4) * 8;

    if (t < 128) {
        ushort4 a = *(const ushort4*)(M2bf + (size_t)(bn * 128 + t) * ACTD);
        ushort4 b = *(const ushort4*)(M2bf + (size_t)(bn * 128 + t) * ACTD + 4);
        M2t[0 * 128 + t] = a.x; M2t[1 * 128 + t] = a.y;
        M2t[2 * 128 + t] = a.z; M2t[3 * 128 + t] = a.w;
        M2t[4 * 128 + t] = b.x; M2t[5 * 128 + t] = b.y;
        M2t[6 * 128 + t] = b.z; M2t[7 * 128 + t] = b.w;
        #pragma unroll
        for (int j = 8; j < 16; ++j) M2t[j * 128 + t] = 0;
    }

    f32x4 acc[4][4];
    #pragma unroll
    for (int i = 0; i < 4; ++i)
        #pragma unroll
        for (int j = 0; j < 4; ++j)
            acc[i][j] = (f32x4){0.f, 0.f, 0.f, 0.f};

    const int rs = t >> 3;                               // 0..31
    const int cs = (t & 7) * 8;                          // hw col, 16B chunks
    #pragma unroll
    for (int kt = 0; kt < OBS; kt += 64) {
        #pragma unroll
        for (int p = 0; p < 4; ++p) {                    // 32 rows/pass
            int r = rs + p * 32;
            int gr = bm * 128 + r; if (gr >= M) gr = M - 1;   // clamp (row discarded later)
            __builtin_amdgcn_global_load_lds(
                (gl_u32*)(A + (size_t)gr * OBS + kt + cs),
                (lds_u32*)(As + r * 64 + cs), 16, 0, 0);
            int gn = bn * 128 + r;
            __builtin_amdgcn_global_load_lds(
                (gl_u32*)(Bt + (size_t)gn * OBS + kt + cs),
                (lds_u32*)(Bs + r * 64 + cs), 16, 0, 0);
        }
        __syncthreads();                                 // drains vmcnt + barrier
        #pragma unroll
        for (int k2 = 0; k2 < 64; k2 += 32) {
            bf16x8 af[4], bfr[4];
            #pragma unroll
            for (int i = 0; i < 4; ++i)
                af[i] = *(const bf16x8*)(As + (wm + i * 16 + l16) * 64 + k2 + kg);
            #pragma unroll
            for (int j = 0; j < 4; ++j)
                bfr[j] = *(const bf16x8*)(Bs + (wn + j * 16 + l16) * 64 + k2 + kg);
            #pragma unroll
            for (int i = 0; i < 4; ++i)
                #pragma unroll
                for (int j = 0; j < 4; ++j)
                    acc[i][j] = __builtin_amdgcn_mfma_f32_16x16x32_bf16(af[i], bfr[j], acc[i][j], 0, 0, 0);
        }
        __syncthreads();                                 // LDS reads done before overwrite
    }

    // relu(acc + bias) -> stage bf16; C/D layout: col=lane&15, row=(lane>>4)*4+reg
    #pragma unroll
    for (int i = 0; i < 4; ++i) {
        int rowb = wm + i * 16 + (lane >> 4) * 4;
        #pragma unroll
        for (int j = 0; j < 4; ++j) {
            int col = wn + j * 16 + l16;
            float bj = bias[bn * 128 + col];
            #pragma unroll
            for (int r = 0; r < 4; ++r)
                stage[(rowb + r) * 136 + col] = f2b(fmaxf(acc[i][j][r] + bj, 0.0f));
        }
    }
    __syncthreads();

    #pragma unroll
    for (int st = 0; st < 2; ++st) {
        int row0 = wv * 32 + st * 16;
        f32x4 z = (f32x4){0.f, 0.f, 0.f, 0.f};
        #pragma unroll
        for (int kt = 0; kt < 128; kt += 32) {
            bf16x8 a = *(const bf16x8*)(stage + (row0 + l16) * 136 + kt + kg);
            bf16x8 b = *(const bf16x8*)(M2t + l16 * 128 + kt + kg);
            z = __builtin_amdgcn_mfma_f32_16x16x32_bf16(a, b, z, 0, 0, 0);
        }
        if (l16 < ACTD) {
            int rowb = bm * 128 + row0 + (lane >> 4) * 4;
            #pragma unroll
            for (int r = 0; r < 4; ++r)
                if (rowb + r < M)
                    atomicAdd(&zacc[(size_t)(rowb + r) * ACTD + l16], z[r]);
        }
    }
}

// ---------- z-aggregation (gather) + tanh + hierarchical pool ----------
// 313 blocks x 256 (32 nodes/block) -> all 256 CUs active (vs 80 at 1024 threads).
// No fence/finalize here (R4 lesson: device-scope fence at 313 blocks cost +22us).
__global__ __launch_bounds__(256) void k_zfinal(const float* __restrict__ zacc,
                                                const float* __restrict__ dinv,
                                                const int* __restrict__ rowptr,
                                                const int* __restrict__ esrc,
                                                const float* __restrict__ coefs,
                                                const float* __restrict__ b2l,
                                                const int* __restrict__ batch,
                                                float* __restrict__ pool,
                                                float* __restrict__ cnt, int n) {
    __shared__ float part[NGR * ACTD];
    __shared__ int   partc[NGR];
    int t = threadIdx.x;
    part[t] = 0.0f; part[t + 256] = 0.0f;
    if (t < NGR) partc[t] = 0;
    __syncthreads();

    int idx = blockIdx.x * 256 + t;
    int i = idx >> 3, j = idx & 7;
    if (i < n) {
        float d = dinv[i];
        float v = zacc[idx] * d * d;
        int e0 = rowptr[i], e1 = rowptr[i + 1];
        for (int e = e0; e < e1; ++e)
            v += coefs[e] * zacc[(size_t)esrc[e] * ACTD + j];
        float tz = tanhf(v + b2l[j]);
        int g = cix(batch[i], NGR);
        atomicAdd(&part[g * ACTD + j], tz);
        if (j == 0) atomicAdd(&partc[g], 1);
    }
    __syncthreads();

    int i0 = (blockIdx.x * 256) >> 3;
    int i1 = (blockIdx.x * 256 + 255) >> 3;
    if (i0 >= n) return;
    if (i1 >= n) i1 = n - 1;
    int g0 = cix(batch[i0], NGR), g1 = cix(batch[i1], NGR);
    int ng = g1 - g0 + 1;                                // sorted batch => contiguous
    for (int u = t; u < ng * ACTD; u += 256)
        atomicAdd(&pool[g0 * ACTD + u], part[g0 * ACTD + u]);
    for (int u = t; u < ng; u += 256) {
        int c = partc[g0 + u];
        if (c) atomicAdd(&cnt[g0 + u], (float)c);
    }
}

__global__ void k_final(const float* __restrict__ pool, const float* __restrict__ cnt,
                        float* __restrict__ out, int total) {
    int i = blockIdx.x * 256 + threadIdx.x;
    if (i < total) out[i] = pool[i] / fmaxf(cnt[i >> 3], 1.0f);
}

// ---------- launch ----------
extern "C" void kernel_launch(void* const* d_in, const int* in_sizes, int n_in,
                              void* d_out, int out_size, void* d_ws, size_t ws_size,
                              hipStream_t stream) {
    const float* x   = (const float*)d_in[0];
    const int*   ei  = (const int*)d_in[1];
    const int*   bat = (const int*)d_in[2];
    const float* W1  = (const float*)d_in[3];
    const float* b1  = (const float*)d_in[4];
    const float* W2  = (const float*)d_in[5];
    const float* b2v = (const float*)d_in[6];
    const float* Wl  = (const float*)d_in[7];
    const float* bl  = (const float*)d_in[8];
    float* out = (float*)d_out;

    const int N = NNODES, E = NEDGES;
    const int* src = ei;
    const int* dst = ei + E;

    // workspace layout — ~4.3 MB total (all offsets multiples of 256 B)
    char* ws = (char*)d_ws;
    size_t off = 0;
    float*  pool   = (float*)(ws + off); off += 2048;
    float*  cnt    = (float*)(ws + off); off += 256;
    float*  dinv   = (float*)(ws + off); off += 40192;                   // N f32
    int*    degi   = (int*)(ws + off);   off += 40192;                   // N i32
    int*    rowptr = (int*)(ws + off);   off += 40448;                   // N+1 i32
    int*    cursor = (int*)(ws + off);   off += 40192;                   // N i32
    int*    esrc   = (int*)(ws + off);   off += (size_t)E * 4;           // 320000
    float*  coefs  = (float*)(ws + off); off += (size_t)E * 4;           // 320000
    float*  b2l    = (float*)(ws + off); off += 256;
    ushort* M2bf   = (ushort*)(ws + off); off += (size_t)HID * ACTD * 2; // 16384
    ushort* Wt1    = (ushort*)(ws + off); off += (size_t)HID * OBS * 2;  // 262144
    float*  zacc   = (float*)(ws + off); off += (size_t)N * ACTD * 4;    // 320000
    ushort* aggbf  = (ushort*)(ws + off); off += (size_t)N * OBS * 2;    // 2560000

    // 1. fused zero + weight prep
    k_prep<<<698, 256, 0, stream>>>(W1, W2, Wl, b2v, bl, Wt1, M2bf, b2l,
                                    zacc, pool, cnt, degi);
    // 2-4. degree(+x L3 warm), scan(+dinv), CSR fill
    k_count<<<(E + 255) / 256, 256, 0, stream>>>(dst, degi, x, E);
    k_scan<<<1, 1024, 0, stream>>>(degi, rowptr, cursor, dinv);
    k_fill<<<(E + 255) / 256, 256, 0, stream>>>(src, dst, dinv, cursor, esrc, coefs, E);

    // 5. layer-1 aggregation (gather) -> bf16  [quarter-wave 4-edge ILP]
    k_aggx<<<(N * 64 + 255) / 256, 256, 0, stream>>>(x, dinv, rowptr, esrc, coefs, aggbf, N);

    // 6. fused GEMM1 + relu + @M2 -> zacc
    k_gemm1_fused<<<dim3((N + 127) / 128, HID / 128), 256, 0, stream>>>(
        aggbf, Wt1, b1, M2bf, zacc, N);

    // 7. z-aggregation (gather) + tanh + hierarchical pool, finalize
    k_zfinal<<<(N * ACTD + 255) / 256, 256, 0, stream>>>(
        zacc, dinv, rowptr, esrc, coefs, b2l, bat, pool, cnt, N);
    k_final<<<2, 256, 0, stream>>>(pool, cnt, out, NGR * ACTD);
}